// Round 13
// baseline (294.714 us; speedup 1.0000x reference)
//
#include <hip/hip_runtime.h>

#define HD 1024
#define BB 64
#define II 512
#define CPAD 32   // ints per counter (128 B)

typedef float f4 __attribute__((ext_vector_type(4)));

__device__ __forceinline__ float fast_tanh(float x) {
    float ax = __builtin_fabsf(x);
    float e  = __builtin_amdgcn_exp2f(ax * -2.8853900817779268f);  // exp(-2|x|)
    float t  = (1.0f - e) * __builtin_amdgcn_rcpf(1.0f + e);
    return x < 0.0f ? -t : t;
}

// out[b][h] = act( sum_k A[b][k] * W[h][k] + bias[h] )
template <int K, bool TANH>
__global__ __launch_bounds__(1024) void k_gemm(const float* __restrict__ A,    // [64][K]
                                               const float* __restrict__ W,    // [1024][K]
                                               const float* __restrict__ bias, // [1024]
                                               float* __restrict__ out,        // [64][1024]
                                               int* __restrict__ syncb)
{
    constexpr int J = K / 256;
    __shared__ float wlds[8 * K];

    int tid  = threadIdx.x;
    if (syncb && blockIdx.x == 0) {
        for (int v = tid; v < 3 * 64 * CPAD; v += 1024) syncb[v] = 0;
    }

    int oct  = blockIdx.x & 127;
    int bg   = blockIdx.x >> 7;          // 0..3
    int h0   = oct * 8;

    {
        const f4* src = (const f4*)(W + (size_t)h0 * K);
        f4* dst = (f4*)wlds;
#pragma unroll
        for (int v = tid; v < 2 * K; v += 1024) dst[v] = src[v];
    }
    __syncthreads();

    int lane = tid & 63;
    int wave = tid >> 6;
    int b    = bg * 16 + wave;

    f4 a[J];
#pragma unroll
    for (int j = 0; j < J; ++j)
        a[j] = *(const f4*)(A + (size_t)b * K + j * 256 + lane * 4);

    float acc[8];
#pragma unroll
    for (int hh = 0; hh < 8; ++hh) {
        const float* wrow = wlds + hh * K;
        float s = 0.f;
#pragma unroll
        for (int j = 0; j < J; ++j) {
            f4 w4 = *(const f4*)(wrow + j * 256 + lane * 4);
            s += a[j].x * w4.x + a[j].y * w4.y + a[j].z * w4.z + a[j].w * w4.w;
        }
        acc[hh] = s;
    }
#pragma unroll
    for (int hh = 0; hh < 8; ++hh)
#pragma unroll
        for (int off = 32; off; off >>= 1)
            acc[hh] += __shfl_xor(acc[hh], off, 64);
    if (lane == 0) {
        f4 o0, o1;
        if (TANH) {
            o0.x = fast_tanh(acc[0] + bias[h0 + 0]);
            o0.y = fast_tanh(acc[1] + bias[h0 + 1]);
            o0.z = fast_tanh(acc[2] + bias[h0 + 2]);
            o0.w = fast_tanh(acc[3] + bias[h0 + 3]);
            o1.x = fast_tanh(acc[4] + bias[h0 + 4]);
            o1.y = fast_tanh(acc[5] + bias[h0 + 5]);
            o1.z = fast_tanh(acc[6] + bias[h0 + 6]);
            o1.w = fast_tanh(acc[7] + bias[h0 + 7]);
        } else {
            o0.x = acc[0] + bias[h0 + 0];
            o0.y = acc[1] + bias[h0 + 1];
            o0.z = acc[2] + bias[h0 + 2];
            o0.w = acc[3] + bias[h0 + 3];
            o1.x = acc[4] + bias[h0 + 4];
            o1.y = acc[5] + bias[h0 + 5];
            o1.z = acc[6] + bias[h0 + 6];
            o1.w = acc[7] + bias[h0 + 7];
        }
        *(f4*)(out + (size_t)b * HD + h0)     = o0;
        *(f4*)(out + (size_t)b * HD + h0 + 4) = o1;
    }
}

// Persistent fused kernel: 256 blocks x 1024 thr (1 block/CU).
// 4 blocks per b; block owns h-slice [sub*256, sub*256+256), 16 rows/wave.
// Phase 1: plastic, acc[16] in regs, NO shuffles in streaming loop (deferred).
// Phase 2: hrc GEMV slice + nm/choice/value partials; sub0 finalizes.
// Phase 3: update, 4-row batches (16 f4 in flight), NT stores.
// Sync: RELEASE arrival, RELAXED poll, single ACQUIRE (R9 protocol).
__global__ __launch_bounds__(1024, 4) void k_fused(
        const float* __restrict__ pw,
        const float* __restrict__ alpha,
        const float* __restrict__ innate,  // [64][1024] = x2@Wfc2.T + bfc2
        const float* __restrict__ x2,      // [64][1024]
        const float* __restrict__ reward,  // [64]
        const float* __restrict__ Wr,      // [1024]
        const float* __restrict__ br,      // [1024]
        const float* __restrict__ Whr,
        const float* __restrict__ bhr,
        const float* __restrict__ Wnm,
        const float* __restrict__ bnm,
        const float* __restrict__ Wch,
        const float* __restrict__ bch,
        const float* __restrict__ Wv,
        const float* __restrict__ bv,
        float* __restrict__ out_choice,
        float* __restrict__ out_nm,
        float* __restrict__ out_value,
        float* __restrict__ out_newpw,
        float* __restrict__ out_hidden,
        float* __restrict__ parts,         // [64][4][4]
        int*   __restrict__ cnt_p,         // [64*CPAD]
        int*   __restrict__ cnt_h,         // [64*CPAD]
        int*   __restrict__ flag_nm)       // [64*CPAD]
{
    __shared__ float xs[HD];
    __shared__ float pre_s[256];
    __shared__ float hid_s[256];
    __shared__ float hplus[HD];
    __shared__ float wred[16][4];
    __shared__ float nm_lds;

    int tid   = threadIdx.x;
    int lane  = tid & 63;
    int wave  = tid >> 6;          // 0..15
    int b     = blockIdx.x >> 2;
    int sub   = blockIdx.x & 3;
    int hbase = sub << 8;
    int hw    = hbase + (wave << 4);   // first h of this wave's 16 rows

    if (tid < 256) ((f4*)xs)[tid] = ((const f4*)(x2 + ((size_t)b << 10)))[tid];
    __syncthreads();

    // ---- Phase 1: plastic stream, acc[16], deferred reduction ----
    const float* pwb = pw    + ((size_t)b << 20) + ((size_t)hw << 10);
    const float* alb = alpha + ((size_t)hw << 10);

    float acc[16];
#pragma unroll
    for (int r = 0; r < 16; ++r) acc[r] = 0.f;

#pragma unroll
    for (int rb = 0; rb < 16; rb += 8) {
#pragma unroll
        for (int j = 0; j < 4; ++j) {
            int i = j * 256 + lane * 4;
            f4 x4 = *(const f4*)(xs + i);
#pragma unroll
            for (int r = 0; r < 8; ++r) {
                int row = rb + r;
                f4 p4 = *(const f4*)(pwb + ((size_t)row << 10) + i);
                f4 a4 = *(const f4*)(alb + ((size_t)row << 10) + i);
                acc[row] += a4.x * p4.x * x4.x + a4.y * p4.y * x4.y +
                            a4.z * p4.z * x4.z + a4.w * p4.w * x4.w;
            }
        }
    }
    // deferred cross-lane reduction, once
#pragma unroll
    for (int r = 0; r < 16; ++r) {
        float v = acc[r];
#pragma unroll
        for (int off = 32; off; off >>= 1) v += __shfl_xor(v, off, 64);
        acc[r] = v;
    }
    if (lane == 0) {
#pragma unroll
        for (int r = 0; r < 16; ++r) {
            int h  = hw + r;
            float pv = innate[(b << 10) + h] + acc[r];
            float hv = fast_tanh(pv);
            pre_s[(wave << 4) + r] = pv;
            hid_s[(wave << 4) + r] = hv;
            out_hidden[(b << 10) + h] = hv;
        }
    }
    __syncthreads();
    if (tid == 0) {
        __hip_atomic_fetch_add(&cnt_p[b * CPAD], 1, __ATOMIC_RELEASE, __HIP_MEMORY_SCOPE_AGENT);
        while (__hip_atomic_load(&cnt_p[b * CPAD], __ATOMIC_RELAXED, __HIP_MEMORY_SCOPE_AGENT) < 4)
            __builtin_amdgcn_s_sleep(1);
        (void)__hip_atomic_load(&cnt_p[b * CPAD], __ATOMIC_ACQUIRE, __HIP_MEMORY_SCOPE_AGENT);
    }
    __syncthreads();

    // ---- Phase 2: hrc rows for slice + partial dots ----
    float rwd = reward[b];
    if (tid < HD) hplus[tid] = out_hidden[(b << 10) + tid] + rwd * Wr[tid] + br[tid];
    __syncthreads();

    float nm0 = 0.f, nm1 = 0.f;
#pragma unroll 1
    for (int rp = 0; rp < 8; ++rp) {
        int h2 = hw + (rp << 1);
        const float* w0 = Whr + ((size_t)h2 << 10);
        const float* w1 = w0 + HD;
        float s0 = 0.f, s1 = 0.f;
#pragma unroll
        for (int j = 0; j < 4; ++j) {
            int i = j * 256 + lane * 4;
            f4 wa = *(const f4*)(w0 + i);
            f4 wb = *(const f4*)(w1 + i);
            f4 h4 = *(const f4*)(hplus + i);
            s0 += wa.x * h4.x + wa.y * h4.y + wa.z * h4.z + wa.w * h4.w;
            s1 += wb.x * h4.x + wb.y * h4.y + wb.z * h4.z + wb.w * h4.w;
        }
#pragma unroll
        for (int off = 32; off; off >>= 1) {
            s0 += __shfl_xor(s0, off, 64);
            s1 += __shfl_xor(s1, off, 64);
        }
        if (lane == 0) {
            float hr0 = fast_tanh(s0 + bhr[h2]);
            float hr1 = fast_tanh(s1 + bhr[h2 + 1]);
            nm0 += Wnm[h2] * hr0 + Wnm[h2 + 1] * hr1;
            nm1 += Wnm[HD + h2] * hr0 + Wnm[HD + h2 + 1] * hr1;
        }
    }
    float cv = 0.f, vv = 0.f;
    if (wave < 4) {
        int idx = (wave << 6) + lane;       // 0..255
        cv = Wch[hbase + idx] * hid_s[idx];
        vv = Wv[hbase + idx] * hid_s[idx];
#pragma unroll
        for (int off = 32; off; off >>= 1) {
            cv += __shfl_xor(cv, off, 64);
            vv += __shfl_xor(vv, off, 64);
        }
    }
    if (lane == 0) {
        wred[wave][0] = nm0; wred[wave][1] = nm1;
        wred[wave][2] = cv;  wred[wave][3] = vv;
    }
    __syncthreads();
    if (tid == 0) {
        float p0 = 0.f, p1 = 0.f, p2 = 0.f, p3 = 0.f;
        for (int w = 0; w < 16; ++w) {
            p0 += wred[w][0]; p1 += wred[w][1];
            p2 += wred[w][2]; p3 += wred[w][3];
        }
        float* pb = parts + b * 16 + sub * 4;
        pb[0] = p0; pb[1] = p1; pb[2] = p2; pb[3] = p3;
        __hip_atomic_fetch_add(&cnt_h[b * CPAD], 1, __ATOMIC_RELEASE, __HIP_MEMORY_SCOPE_AGENT);
        if (sub == 0) {
            while (__hip_atomic_load(&cnt_h[b * CPAD], __ATOMIC_RELAXED, __HIP_MEMORY_SCOPE_AGENT) < 4)
                __builtin_amdgcn_s_sleep(1);
            (void)__hip_atomic_load(&cnt_h[b * CPAD], __ATOMIC_ACQUIRE, __HIP_MEMORY_SCOPE_AGENT);
            float s0 = 0.f, s1 = 0.f, s2 = 0.f, s3 = 0.f;
            for (int q = 0; q < 4; ++q) {          // fixed order -> deterministic
                const float* pp = parts + b * 16 + q * 4;
                s0 += pp[0]; s1 += pp[1]; s2 += pp[2]; s3 += pp[3];
            }
            float n0 = fast_tanh(s0 + bnm[0]);
            float n1 = fast_tanh(s1 + bnm[1]);
            out_nm[b] = n0 - n1;
            float z = s2 + bch[0];
            out_choice[b] = __builtin_amdgcn_rcpf(1.0f + __builtin_amdgcn_exp2f(-z * 1.4426950408889634f));
            out_value[b]  = s3 + bv[0];
            __hip_atomic_store(&flag_nm[b * CPAD], 1, __ATOMIC_RELEASE, __HIP_MEMORY_SCOPE_AGENT);
        }
        while (__hip_atomic_load(&flag_nm[b * CPAD], __ATOMIC_RELAXED, __HIP_MEMORY_SCOPE_AGENT) == 0)
            __builtin_amdgcn_s_sleep(1);
        (void)__hip_atomic_load(&flag_nm[b * CPAD], __ATOMIC_ACQUIRE, __HIP_MEMORY_SCOPE_AGENT);
        nm_lds = out_nm[b];
    }
    __syncthreads();
    float nb = nm_lds;

    // ---- Phase 3: update, 4-row batches (16 f4 in flight), pw from L3 ----
    float* outb = out_newpw + ((size_t)b << 20) + ((size_t)hw << 10);
#pragma unroll
    for (int rp = 0; rp < 4; ++rp) {
        f4 p[4][4];
#pragma unroll
        for (int r = 0; r < 4; ++r)
#pragma unroll
            for (int j = 0; j < 4; ++j)
                p[r][j] = *(const f4*)(pwb + ((size_t)(rp * 4 + r) << 10) + j * 256 + lane * 4);
#pragma unroll
        for (int r = 0; r < 4; ++r) {
            float ps = pre_s[(wave << 4) + rp * 4 + r];
#pragma unroll
            for (int j = 0; j < 4; ++j) {
                int i = j * 256 + lane * 4;
                f4 x4 = *(const f4*)(xs + i);
                f4 o;
                o.x = fminf(fmaxf(p[r][j].x + nb * fast_tanh(ps * x4.x), -50.f), 50.f);
                o.y = fminf(fmaxf(p[r][j].y + nb * fast_tanh(ps * x4.y), -50.f), 50.f);
                o.z = fminf(fmaxf(p[r][j].z + nb * fast_tanh(ps * x4.z), -50.f), 50.f);
                o.w = fminf(fmaxf(p[r][j].w + nb * fast_tanh(ps * x4.w), -50.f), 50.f);
                __builtin_nontemporal_store(o, (f4*)(outb + ((size_t)(rp * 4 + r) << 10) + i));
            }
        }
    }
}

extern "C" void kernel_launch(void* const* d_in, const int* in_sizes, int n_in,
                              void* d_out, int out_size, void* d_ws, size_t ws_size,
                              hipStream_t stream) {
    const float* items  = (const float*)d_in[0];
    const float* pw     = (const float*)d_in[1];
    const float* reward = (const float*)d_in[2];
    const float* We     = (const float*)d_in[3];
    const float* be     = (const float*)d_in[4];
    const float* W1     = (const float*)d_in[5];
    const float* b1     = (const float*)d_in[6];
    const float* W2     = (const float*)d_in[7];
    const float* b2     = (const float*)d_in[8];
    const float* Wfc2   = (const float*)d_in[9];
    const float* bfc2   = (const float*)d_in[10];
    const float* Whr    = (const float*)d_in[11];
    const float* bhr    = (const float*)d_in[12];
    const float* Wch    = (const float*)d_in[13];
    const float* bch    = (const float*)d_in[14];
    const float* Wr     = (const float*)d_in[15];
    const float* br     = (const float*)d_in[16];
    const float* Wnm    = (const float*)d_in[17];
    const float* bnm    = (const float*)d_in[18];
    const float* alpha  = (const float*)d_in[19];
    const float* Wv     = (const float*)d_in[20];
    const float* bv     = (const float*)d_in[21];

    float* ws     = (float*)d_ws;
    float* x0     = ws;                   // 65536
    float* x1     = ws + 65536;           // 65536
    float* x2     = ws + 131072;          // 65536
    float* innate = ws + 196608;          // 65536
    float* parts  = ws + 262144;          // 1024
    int*   syncb  = (int*)(ws + 263168);  // 3 * 64 * CPAD ints
    int*   cnt_p   = syncb;
    int*   cnt_h   = syncb + 64 * CPAD;
    int*   flag_nm = syncb + 128 * CPAD;

    float* out        = (float*)d_out;
    float* out_choice = out;                        // 64
    float* out_nm     = out + 64;                   // 64
    float* out_value  = out + 128;                  // 64
    float* out_newpw  = out + 192;                  // 67,108,864
    float* out_hidden = out + 192 + BB * HD * HD;   // 65,536

    k_gemm<II, true ><<<512, 1024, 0, stream>>>(items, We, be, x0, syncb);
    k_gemm<HD, true ><<<512, 1024, 0, stream>>>(x0, W1, b1, x1, nullptr);
    k_gemm<HD, true ><<<512, 1024, 0, stream>>>(x1, W2, b2, x2, nullptr);
    k_gemm<HD, false><<<512, 1024, 0, stream>>>(x2, Wfc2, bfc2, innate, nullptr);
    k_fused<<<256, 1024, 0, stream>>>(pw, alpha, innate, x2, reward, Wr, br,
                                      Whr, bhr, Wnm, bnm, Wch, bch, Wv, bv,
                                      out_choice, out_nm, out_value, out_newpw,
                                      out_hidden, parts, cnt_p, cnt_h, flag_nm);
}